// Round 9
// baseline (244.380 us; speedup 1.0000x reference)
//
#include <hip/hip_runtime.h>
#include <math.h>

#define C_    1204
#define C4_   301    // C_/4 float4s per row
#define NABLK 1024   // A-blocks: 16 rows each (4 waves x 4 rows)
#define NGBLK 80     // G-blocks: cw2^T * cga partials (16 i-chunks x 5 j-tiles)
#define NDBLK 5      // diag blocks: cga[j][j]
#define GYLEN 76     // ceil(1204/16)
#define NSGRP 8      // S atomic contention groups
#define NTOT  (NABLK + NGBLK + NDBLK + 1)

__device__ __forceinline__ float waveReduceSum(float v){
    #pragma unroll
    for (int o = 32; o > 0; o >>= 1) v += __shfl_xor(v, o, 64);
    return v;
}
__device__ __forceinline__ float4 exp4v(float4 v){
    return float4{__expf(v.x), __expf(v.y), __expf(v.z), __expf(v.w)};
}
__device__ __forceinline__ float hsum4(float4 v){ return v.x + v.y + v.z + v.w; }

// block-wide sumexp of logits (no-max: |logits| <= ~0.05, exact within fp)
__device__ __forceinline__ float blockSumExpLogits(const float* __restrict__ logits,
                                                   float* red, int t){
    float s = 0.f;
    #pragma unroll
    for (int k = 0; k < 5; ++k){ int j = t + k * 256; if (j < C_) s += __expf(logits[j]); }
    red[t] = s; __syncthreads();
    for (int o = 128; o > 0; o >>= 1){ if (t < o) red[t] += red[t+o]; __syncthreads(); }
    float r = red[0]; __syncthreads();
    return r;
}

__global__ __launch_bounds__(256)
void k_mega(const float* __restrict__ cs, const int* __restrict__ label,
            const float* __restrict__ w, const float* __restrict__ cwb,
            const float* __restrict__ logits, const float* __restrict__ cga,
            const float* __restrict__ wm0, float* __restrict__ out,
            float* suma, float* sumb, float* S8, unsigned* done,
            float* __restrict__ part1, float* __restrict__ part2,
            float* __restrict__ Gpart, float* __restrict__ diagG, int Nn)
{
    __shared__ float smem[C_ + 512];
    const int b = blockIdx.x;
    const int tid = threadIdx.x;

    if (b < NABLK){
        // ======== A-block: 16 rows — sumexp + focal + S column-sum ========
        float* Sloc = smem;
        float* lr1  = smem + C_;
        float* lr2  = smem + C_ + 4;
        int lane = tid & 63, wid = tid >> 6;
        bool has4 = lane < (C4_ - 256);   // 45 tail float4s

        for (int j = tid; j < C_; j += 256) Sloc[j] = 0.f;

        // per-wave logits sumexp -> K = C/sum (for cw2[l])
        const float4* lg4 = reinterpret_cast<const float4*>(logits);
        float slog = hsum4(exp4v(lg4[lane])) + hsum4(exp4v(lg4[lane + 64]))
                   + hsum4(exp4v(lg4[lane + 128])) + hsum4(exp4v(lg4[lane + 192]));
        if (has4) slog += hsum4(exp4v(lg4[lane + 256]));
        slog = waveReduceSum(slog);
        float Klog = (float)C_ / slog;

        float4 acc0 = {0,0,0,0}, acc1 = {0,0,0,0}, acc2 = {0,0,0,0},
               acc3 = {0,0,0,0}, acc4 = {0,0,0,0};
        float accL = 0.f, accT = 0.f;
        int rowbase = b * 16 + wid * 4;

        #pragma unroll 1
        for (int pr = 0; pr < 2; ++pr){
            int nA = rowbase + pr * 2, nB = nA + 1;
            const float4* rowA = reinterpret_cast<const float4*>(cs + (size_t)nA * C_);
            const float4* rowB = reinterpret_cast<const float4*>(cs + (size_t)nB * C_);

            float4 ea0 = rowA[lane], ea1 = rowA[lane + 64], ea2 = rowA[lane + 128], ea3 = rowA[lane + 192];
            float4 eb0 = rowB[lane], eb1 = rowB[lane + 64], eb2 = rowB[lane + 128], eb3 = rowB[lane + 192];
            float4 ea4 = {0,0,0,0}, eb4 = {0,0,0,0};
            if (has4){ ea4 = rowA[lane + 256]; eb4 = rowB[lane + 256]; }

            ea0 = exp4v(ea0); ea1 = exp4v(ea1); ea2 = exp4v(ea2); ea3 = exp4v(ea3);
            eb0 = exp4v(eb0); eb1 = exp4v(eb1); eb2 = exp4v(eb2); eb3 = exp4v(eb3);
            if (has4){ ea4 = exp4v(ea4); eb4 = exp4v(eb4); }

            float sA = hsum4(ea0) + hsum4(ea1) + hsum4(ea2) + hsum4(ea3) + hsum4(ea4);
            float sB = hsum4(eb0) + hsum4(eb1) + hsum4(eb2) + hsum4(eb3) + hsum4(eb4);
            sA = waveReduceSum(sA);
            sB = waveReduceSum(sB);

            float coefv = 0.f;
            if (lane < 2){
                int   n = (lane == 0) ? nA : nB;
                float s = (lane == 0) ? sA : sB;
                int l = label[n];
                float x = cs[(size_t)n * C_ + l];       // L1-hot, row just streamed
                float logp = x - __logf(s);             // no-max softmax: same math
                float p = __expf(logp);
                float lossc = (1.f - p) * (-logp);      // GAMMA = 1
                float tw = fminf(fmaxf(cwb[l], 1.f/3.f), 5.f);
                float wn = w[n];
                float pp = p + 1e-5f;                   // softmax + 1e-5 at true class
                float fg = wn * ((1.f - pp) / pp - __logf(pp));
                float an = fg * pp;
                atomicAdd(&suma[l], an);
                atomicAdd(&sumb[l], an * pp);
                float c2 = Klog * __expf(logits[l]);    // cw2[l], local recompute
                coefv = c2 * an / s;                    // S-weight for this row
                accL += lossc * tw * wn;
                accT += tw;
            }
            float cA = __shfl(coefv, 0, 64);
            float cB = __shfl(coefv, 1, 64);

            acc0.x += cA*ea0.x + cB*eb0.x; acc0.y += cA*ea0.y + cB*eb0.y;
            acc0.z += cA*ea0.z + cB*eb0.z; acc0.w += cA*ea0.w + cB*eb0.w;
            acc1.x += cA*ea1.x + cB*eb1.x; acc1.y += cA*ea1.y + cB*eb1.y;
            acc1.z += cA*ea1.z + cB*eb1.z; acc1.w += cA*ea1.w + cB*eb1.w;
            acc2.x += cA*ea2.x + cB*eb2.x; acc2.y += cA*ea2.y + cB*eb2.y;
            acc2.z += cA*ea2.z + cB*eb2.z; acc2.w += cA*ea2.w + cB*eb2.w;
            acc3.x += cA*ea3.x + cB*eb3.x; acc3.y += cA*ea3.y + cB*eb3.y;
            acc3.z += cA*ea3.z + cB*eb3.z; acc3.w += cA*ea3.w + cB*eb3.w;
            if (has4){
                acc4.x += cA*ea4.x + cB*eb4.x; acc4.y += cA*ea4.y + cB*eb4.y;
                acc4.z += cA*ea4.z + cB*eb4.z; acc4.w += cA*ea4.w + cB*eb4.w;
            }
        }

        accL += __shfl_xor(accL, 1, 64);
        accT += __shfl_xor(accT, 1, 64);
        if (lane == 0){ lr1[wid] = accL; lr2[wid] = accT; }

        // wave-sequential accumulation into Sloc (no LDS atomics)
        float4* Sloc4 = reinterpret_cast<float4*>(Sloc);
        __syncthreads();
        #pragma unroll
        for (int wv = 0; wv < 4; ++wv){
            if (wid == wv){
                float4 t0 = Sloc4[lane      ]; t0.x+=acc0.x; t0.y+=acc0.y; t0.z+=acc0.z; t0.w+=acc0.w; Sloc4[lane      ] = t0;
                float4 t1 = Sloc4[lane +  64]; t1.x+=acc1.x; t1.y+=acc1.y; t1.z+=acc1.z; t1.w+=acc1.w; Sloc4[lane +  64] = t1;
                float4 t2 = Sloc4[lane + 128]; t2.x+=acc2.x; t2.y+=acc2.y; t2.z+=acc2.z; t2.w+=acc2.w; Sloc4[lane + 128] = t2;
                float4 t3 = Sloc4[lane + 192]; t3.x+=acc3.x; t3.y+=acc3.y; t3.z+=acc3.z; t3.w+=acc3.w; Sloc4[lane + 192] = t3;
                if (has4){
                    float4 t4 = Sloc4[lane + 256]; t4.x+=acc4.x; t4.y+=acc4.y; t4.z+=acc4.z; t4.w+=acc4.w; Sloc4[lane + 256] = t4;
                }
            }
            __syncthreads();
        }

        float* Sg = S8 + (size_t)(b & (NSGRP - 1)) * C_;
        for (int j = tid; j < C_; j += 256) atomicAdd(&Sg[j], Sloc[j]);

        if (tid == 0){
            part1[b] = lr1[0] + lr1[1] + lr1[2] + lr1[3];
            part2[b] = lr2[0] + lr2[1] + lr2[2] + lr2[3];
        }
    } else if (b < NABLK + NGBLK){
        // ======== G-block: Gpart[ic][j] = sum_{i in chunk} cw2[i]*cga[i][j] ========
        int gb = b - NABLK;
        int jt = gb % 5, ic = gb / 5;
        float* red  = smem;
        float* elog = smem + 256;
        float slog = blockSumExpLogits(logits, red, tid);
        float K = (float)C_ / slog;
        int i0 = ic * GYLEN, i1 = min(i0 + GYLEN, C_);
        if (tid < i1 - i0) elog[tid] = __expf(logits[i0 + tid]);
        __syncthreads();
        int j = jt * 256 + tid;
        if (j < C_){
            float p = 0.f;
            #pragma unroll 4
            for (int i = i0; i < i1; ++i) p += elog[i - i0] * cga[(size_t)i * C_ + j];
            Gpart[ic * C_ + j] = K * p;
        }
    } else if (b < NABLK + NGBLK + NDBLK){
        // ======== diag block: diagG[j] = cga[j][j] ========
        int j = (b - NABLK - NGBLK) * 256 + tid;
        if (j < C_) diagG[j] = cga[(size_t)j * C_ + j];
    } else {
        // ======== cw2 output block ========
        float* red = smem;
        float slog = blockSumExpLogits(logits, red, tid);
        float K = (float)C_ / slog;
        #pragma unroll
        for (int k = 0; k < 5; ++k){
            int j = tid + k * 256;
            if (j < C_) out[2 + j] = K * __expf(logits[j]);
        }
    }

    // ================= last-block-finishes protocol =================
    __threadfence();
    __syncthreads();
    __shared__ unsigned isLast;
    if (tid == 0){
        unsigned prev = atomicAdd(done, 1u);
        isLast = (prev == (unsigned)(NTOT - 1)) ? 1u : 0u;
    }
    __syncthreads();
    if (!isLast) return;
    __threadfence();

    // ================= finale (former k_last) =================
    {
        float* tcw  = smem;
        float* red  = smem + C_;
        float* red2 = smem + C_ + 256;
        int t = tid;
        __syncthreads();

        float slog = blockSumExpLogits(logits, red, t);
        float K = (float)C_ / slog;

        float p1 = 0.f, p2 = 0.f;
        for (int k = t; k < NABLK; k += 256){ p1 += part1[k]; p2 += part2[k]; }
        red[t] = p1; red2[t] = p2; __syncthreads();
        for (int o = 128; o > 0; o >>= 1){
            if (t < o){ red[t] += red[t+o]; red2[t] += red2[t+o]; }
            __syncthreads();
        }
        float sumLoss = red[0], sumT = red2[0];
        __syncthreads();

        // E = 1e-5 * dot(cw2, suma)
        float pe = 0.f;
        #pragma unroll
        for (int k = 0; k < 5; ++k){
            int j = t + k * 256;
            if (j < C_) pe += K * __expf(logits[j]) * suma[j];
        }
        red[t] = pe; __syncthreads();
        for (int o = 128; o > 0; o >>= 1){ if (t < o) red[t] += red[t+o]; __syncthreads(); }
        float E = red[0] * 1e-5f;
        __syncthreads();

        float scale = 100.f / (float)Nn;
        float psum = 0.f;
        #pragma unroll
        for (int k = 0; k < 5; ++k){
            int j = t + k * 256;
            if (j < C_ - 1){
                float c2 = K * __expf(logits[j]);
                float G = 0.f;
                #pragma unroll
                for (int y = 0; y < 16; ++y) G += Gpart[y * C_ + j];
                float Sj = 0.f;
                #pragma unroll
                for (int g = 0; g < NSGRP; ++g) Sj += S8[g * C_ + j];
                float tcol  = 0.999f * G + 0.001f * scale * (Sj + E - c2 * suma[j]);
                float diagA = 0.999f * diagG[j] - 0.001f * scale * (suma[j] - sumb[j]);
                float v = tcol / (-diagA + 1e-6f) + c2;
                tcw[j] = v; psum += v;       // sum of UNclipped first C-1 values
            }
        }
        red[t] = psum; __syncthreads();
        for (int o = 128; o > 0; o >>= 1){ if (t < o) red[t] += red[t+o]; __syncthreads(); }
        if (t == 0) tcw[C_ - 1] = (float)C_ - red[0];
        __syncthreads();
        float sq = 0.f;
        #pragma unroll
        for (int k = 0; k < 5; ++k){
            int j = t + k * 256;
            if (j < C_){
                float hi = (j == C_ - 1) ? 1.f : 5.f;  // clip(.,1/3,5); last clip(.,1/3,1)
                float v = fminf(fmaxf(tcw[j], 1.f/3.f), hi);
                float d = logf(v) - logits[j];
                sq += d * d;
            }
        }
        red[t] = sq; __syncthreads();
        for (int o = 128; o > 0; o >>= 1){ if (t < o) red[t] += red[t+o]; __syncthreads(); }
        if (t == 0){
            float wm = 0.999f * wm0[0] + 0.001f * (sumT / (float)Nn);
            out[0] = sumLoss / ((float)Nn * wm);  // loss (SELF_LOSS_WEIGHT = 1)
            out[1] = red[0] / (float)C_;          // loss_grad
        }
    }
}

extern "C" void kernel_launch(void* const* d_in, const int* in_sizes, int n_in,
                              void* d_out, int out_size, void* d_ws, size_t ws_size,
                              hipStream_t stream){
    (void)n_in; (void)out_size; (void)ws_size;
    const float* cs     = (const float*)d_in[0];
    const int*   label  = (const int*)  d_in[1];
    const float* weight = (const float*)d_in[2];
    const float* logits = (const float*)d_in[3];
    const float* cwb    = (const float*)d_in[4];
    const float* cga    = (const float*)d_in[5];
    const float* wm0    = (const float*)d_in[6];
    float* out = (float*)d_out;
    int N = in_sizes[1];                       // 16384

    // workspace layout (float elements; 16B-aligned)
    float* ws      = (float*)d_ws;
    float* suma    = ws;                       // C   } zeroed by memset
    float* sumb    = suma + C_;                // C   }
    float* S8      = sumb + C_;                // 8C  }
    unsigned* done = (unsigned*)(S8 + NSGRP * C_); // 1 (+pad) }
    float* part1   = (float*)done + 4;         // NABLK
    float* part2   = part1 + NABLK;            // NABLK
    float* Gpart   = part2 + NABLK;            // 16*C
    float* diagG   = Gpart + 16 * C_;          // C

    hipMemsetAsync(d_ws, 0, (size_t)(2 + NSGRP) * C_ * 4 + 16, stream);
    k_mega <<<NTOT, 256, 0, stream>>>(cs, label, weight, cwb, logits, cga, wm0, out,
                                      suma, sumb, S8, done, part1, part2, Gpart, diagG, N);
}

// Round 10
// 146.113 us; speedup vs baseline: 1.6725x; 1.6725x over previous
//
#include <hip/hip_runtime.h>
#include <math.h>

#define C_    1204
#define C4_   301    // C_/4 float4s per row
#define NABLK 512    // A-blocks: 32 rows each (4 waves x 8 rows)
#define NGBLK 80     // G-blocks: cw2^T * cga partials (16 i-chunks x 5 j-tiles)
#define NDBLK 5      // diag blocks: cga[j][j]
#define GYLEN 76     // ceil(1204/16)
#define NSGRP 16     // S atomic contention groups

__device__ __forceinline__ float waveReduceSum(float v){
    #pragma unroll
    for (int o = 32; o > 0; o >>= 1) v += __shfl_xor(v, o, 64);
    return v;
}
__device__ __forceinline__ float4 exp4v(float4 v){
    return float4{__expf(v.x), __expf(v.y), __expf(v.z), __expf(v.w)};
}
__device__ __forceinline__ float hsum4(float4 v){ return v.x + v.y + v.z + v.w; }

// ---- pre: single block — cw2 = softmax(logits)*C (zeroing now via memset) ----
__global__ void k_pre(const float* __restrict__ logits, float* cw2, float* out){
    __shared__ float red[256];
    int t = threadIdx.x;
    float x[5]; float m = -3.402823466e38f;
    #pragma unroll
    for (int k = 0; k < 5; ++k){
        int j = t + k * 256;
        x[k] = (j < C_) ? logits[j] : -3.402823466e38f;
        m = fmaxf(m, x[k]);
    }
    red[t] = m; __syncthreads();
    for (int o = 128; o > 0; o >>= 1){ if (t < o) red[t] = fmaxf(red[t], red[t+o]); __syncthreads(); }
    float bm = red[0]; __syncthreads();
    float ss = 0.f;
    #pragma unroll
    for (int k = 0; k < 5; ++k){ int j = t + k * 256; if (j < C_) ss += __expf(x[k] - bm); }
    red[t] = ss; __syncthreads();
    for (int o = 128; o > 0; o >>= 1){ if (t < o) red[t] += red[t+o]; __syncthreads(); }
    float bs = red[0]; __syncthreads();
    #pragma unroll
    for (int k = 0; k < 5; ++k){
        int j = t + k * 256;
        if (j < C_){ float v = __expf(x[k] - bm) / bs * (float)C_; cw2[j] = v; out[2 + j] = v; }
    }
}

// ---- single pass over cs: sumexp + focal terms + S column-sum, all fused.
//      blocks 0..511: 32 rows each. blocks 512..591: G partials.
//      blocks 592..596: diagG. ----
__global__ void k_rows(const float* __restrict__ cs, const int* __restrict__ label,
                       const float* __restrict__ w, const float* __restrict__ cwb,
                       const float* __restrict__ cw2, const float* __restrict__ cga,
                       float* suma, float* sumb, float* S16,
                       float* __restrict__ part1, float* __restrict__ part2,
                       float* __restrict__ Gpart, float* __restrict__ diagG){
    int b = blockIdx.x;
    int tid = threadIdx.x;

    if (b >= NABLK){
        int gb = b - NABLK;
        if (gb < NGBLK){
            int jt = gb % 5, ic = gb / 5;
            int j = jt * 256 + tid;
            if (j < C_){
                int i0 = ic * GYLEN, i1 = min(i0 + GYLEN, C_);
                float p = 0.f;
                #pragma unroll 4
                for (int i = i0; i < i1; ++i) p += cw2[i] * cga[(size_t)i * C_ + j];
                Gpart[ic * C_ + j] = p;
            }
        } else {
            int j = (gb - NGBLK) * 256 + tid;
            if (j < C_) diagG[j] = cga[(size_t)j * C_ + j];
        }
        return;
    }

    __shared__ float Sloc[C_];
    __shared__ float lr1[4], lr2[4];
    int lane = tid & 63, wid = tid >> 6;
    bool has4 = lane < (C4_ - 256);   // 45 tail float4s

    for (int j = tid; j < C_; j += 256) Sloc[j] = 0.f;

    float4 acc0 = {0,0,0,0}, acc1 = {0,0,0,0}, acc2 = {0,0,0,0},
           acc3 = {0,0,0,0}, acc4 = {0,0,0,0};
    float accL = 0.f, accT = 0.f;
    int rowbase = b * 32 + wid * 8;

    #pragma unroll 1
    for (int pr = 0; pr < 4; ++pr){
        int nA = rowbase + pr * 2, nB = nA + 1;
        const float4* rowA = reinterpret_cast<const float4*>(cs + (size_t)nA * C_);
        const float4* rowB = reinterpret_cast<const float4*>(cs + (size_t)nB * C_);

        float4 ea0 = rowA[lane], ea1 = rowA[lane + 64], ea2 = rowA[lane + 128], ea3 = rowA[lane + 192];
        float4 eb0 = rowB[lane], eb1 = rowB[lane + 64], eb2 = rowB[lane + 128], eb3 = rowB[lane + 192];
        float4 ea4 = {0,0,0,0}, eb4 = {0,0,0,0};
        if (has4){ ea4 = rowA[lane + 256]; eb4 = rowB[lane + 256]; }

        ea0 = exp4v(ea0); ea1 = exp4v(ea1); ea2 = exp4v(ea2); ea3 = exp4v(ea3);
        eb0 = exp4v(eb0); eb1 = exp4v(eb1); eb2 = exp4v(eb2); eb3 = exp4v(eb3);
        if (has4){ ea4 = exp4v(ea4); eb4 = exp4v(eb4); }

        float sA = hsum4(ea0) + hsum4(ea1) + hsum4(ea2) + hsum4(ea3) + hsum4(ea4);
        float sB = hsum4(eb0) + hsum4(eb1) + hsum4(eb2) + hsum4(eb3) + hsum4(eb4);
        sA = waveReduceSum(sA);
        sB = waveReduceSum(sB);

        float coefv = 0.f;
        if (lane < 2){
            int   n = (lane == 0) ? nA : nB;
            float s = (lane == 0) ? sA : sB;
            int l = label[n];
            float x = cs[(size_t)n * C_ + l];       // L1-hot, row just streamed
            float logp = x - __logf(s);             // no-max softmax: same math
            float p = __expf(logp);
            float lossc = (1.f - p) * (-logp);      // GAMMA = 1
            float tw = fminf(fmaxf(cwb[l], 1.f/3.f), 5.f);
            float wn = w[n];
            float pp = p + 1e-5f;                   // softmax + 1e-5 at true class
            float fg = wn * ((1.f - pp) / pp - __logf(pp));
            float an = fg * pp;
            atomicAdd(&suma[l], an);
            atomicAdd(&sumb[l], an * pp);
            coefv = cw2[l] * an / s;                // S-weight for this row
            accL += lossc * tw * wn;
            accT += tw;
        }
        float cA = __shfl(coefv, 0, 64);
        float cB = __shfl(coefv, 1, 64);

        acc0.x += cA*ea0.x + cB*eb0.x; acc0.y += cA*ea0.y + cB*eb0.y;
        acc0.z += cA*ea0.z + cB*eb0.z; acc0.w += cA*ea0.w + cB*eb0.w;
        acc1.x += cA*ea1.x + cB*eb1.x; acc1.y += cA*ea1.y + cB*eb1.y;
        acc1.z += cA*ea1.z + cB*eb1.z; acc1.w += cA*ea1.w + cB*eb1.w;
        acc2.x += cA*ea2.x + cB*eb2.x; acc2.y += cA*ea2.y + cB*eb2.y;
        acc2.z += cA*ea2.z + cB*eb2.z; acc2.w += cA*ea2.w + cB*eb2.w;
        acc3.x += cA*ea3.x + cB*eb3.x; acc3.y += cA*ea3.y + cB*eb3.y;
        acc3.z += cA*ea3.z + cB*eb3.z; acc3.w += cA*ea3.w + cB*eb3.w;
        if (has4){
            acc4.x += cA*ea4.x + cB*eb4.x; acc4.y += cA*ea4.y + cB*eb4.y;
            acc4.z += cA*ea4.z + cB*eb4.z; acc4.w += cA*ea4.w + cB*eb4.w;
        }
    }

    // pair-reduce loss terms (lanes 0,1 hold per-row values)
    accL += __shfl_xor(accL, 1, 64);
    accT += __shfl_xor(accT, 1, 64);
    if (lane == 0){ lr1[wid] = accL; lr2[wid] = accT; }

    // wave-sequential accumulation into Sloc (no LDS atomics)
    float4* Sloc4 = reinterpret_cast<float4*>(Sloc);
    __syncthreads();
    #pragma unroll
    for (int wv = 0; wv < 4; ++wv){
        if (wid == wv){
            float4 t0 = Sloc4[lane      ]; t0.x+=acc0.x; t0.y+=acc0.y; t0.z+=acc0.z; t0.w+=acc0.w; Sloc4[lane      ] = t0;
            float4 t1 = Sloc4[lane +  64]; t1.x+=acc1.x; t1.y+=acc1.y; t1.z+=acc1.z; t1.w+=acc1.w; Sloc4[lane +  64] = t1;
            float4 t2 = Sloc4[lane + 128]; t2.x+=acc2.x; t2.y+=acc2.y; t2.z+=acc2.z; t2.w+=acc2.w; Sloc4[lane + 128] = t2;
            float4 t3 = Sloc4[lane + 192]; t3.x+=acc3.x; t3.y+=acc3.y; t3.z+=acc3.z; t3.w+=acc3.w; Sloc4[lane + 192] = t3;
            if (has4){
                float4 t4 = Sloc4[lane + 256]; t4.x+=acc4.x; t4.y+=acc4.y; t4.z+=acc4.z; t4.w+=acc4.w; Sloc4[lane + 256] = t4;
            }
        }
        __syncthreads();
    }

    // block partial -> grouped global atomics (32 blocks/address)
    float* Sg = S16 + (size_t)(b & (NSGRP - 1)) * C_;
    for (int j = tid; j < C_; j += 256) atomicAdd(&Sg[j], Sloc[j]);

    if (tid == 0){
        part1[b] = lr1[0] + lr1[1] + lr1[2] + lr1[3];
        part2[b] = lr2[0] + lr2[1] + lr2[2] + lr2[3];
    }
}

// ---- last: loss partials, E, tcol/diag closed forms, tcw, clips, outputs ----
__global__ void k_last(const float* __restrict__ S16, const float* __restrict__ Gpart,
                       const float* __restrict__ diagG, const float* __restrict__ suma,
                       const float* __restrict__ sumb, const float* __restrict__ cw2,
                       const float* __restrict__ logits, const float* __restrict__ part1,
                       const float* __restrict__ part2, const float* __restrict__ wm0,
                       float* out, int Nn){
    __shared__ float tcw[C_];
    __shared__ float red[256];
    __shared__ float red2[256];
    int t = threadIdx.x;

    float p1 = 0.f, p2 = 0.f;
    for (int k = t; k < NABLK; k += 256){ p1 += part1[k]; p2 += part2[k]; }
    red[t] = p1; red2[t] = p2; __syncthreads();
    for (int o = 128; o > 0; o >>= 1){
        if (t < o){ red[t] += red[t+o]; red2[t] += red2[t+o]; }
        __syncthreads();
    }
    float sumLoss = red[0], sumT = red2[0];
    __syncthreads();

    // E = 1e-5 * dot(cw2, suma)
    float pe = 0.f;
    #pragma unroll
    for (int k = 0; k < 5; ++k){
        int j = t + k * 256;
        if (j < C_) pe += cw2[j] * suma[j];
    }
    red[t] = pe; __syncthreads();
    for (int o = 128; o > 0; o >>= 1){ if (t < o) red[t] += red[t+o]; __syncthreads(); }
    float E = red[0] * 1e-5f;
    __syncthreads();

    float scale = 100.f / (float)Nn;
    float psum = 0.f;
    #pragma unroll
    for (int k = 0; k < 5; ++k){
        int j = t + k * 256;
        if (j < C_ - 1){
            float G = 0.f;
            #pragma unroll
            for (int y = 0; y < 16; ++y) G += Gpart[y * C_ + j];
            float Sj = 0.f;
            #pragma unroll
            for (int g = 0; g < NSGRP; ++g) Sj += S16[g * C_ + j];
            float tcol  = 0.999f * G + 0.001f * scale * (Sj + E - cw2[j] * suma[j]);
            float diagA = 0.999f * diagG[j] - 0.001f * scale * (suma[j] - sumb[j]);
            float v = tcol / (-diagA + 1e-6f) + cw2[j];
            tcw[j] = v; psum += v;           // sum of UNclipped first C-1 values
        }
    }
    red[t] = psum; __syncthreads();
    for (int o = 128; o > 0; o >>= 1){ if (t < o) red[t] += red[t+o]; __syncthreads(); }
    if (t == 0) tcw[C_ - 1] = (float)C_ - red[0];
    __syncthreads();
    float sq = 0.f;
    #pragma unroll
    for (int k = 0; k < 5; ++k){
        int j = t + k * 256;
        if (j < C_){
            float hi = (j == C_ - 1) ? 1.f : 5.f;   // clip(.,1/3,5); last clip(.,1/3,1)
            float v = fminf(fmaxf(tcw[j], 1.f/3.f), hi);
            float d = logf(v) - logits[j];
            sq += d * d;
        }
    }
    red[t] = sq; __syncthreads();
    for (int o = 128; o > 0; o >>= 1){ if (t < o) red[t] += red[t+o]; __syncthreads(); }
    if (t == 0){
        float wm = 0.999f * wm0[0] + 0.001f * (sumT / (float)Nn);
        out[0] = sumLoss / ((float)Nn * wm);   // loss (SELF_LOSS_WEIGHT = 1)
        out[1] = red[0] / (float)C_;           // loss_grad
    }
}

extern "C" void kernel_launch(void* const* d_in, const int* in_sizes, int n_in,
                              void* d_out, int out_size, void* d_ws, size_t ws_size,
                              hipStream_t stream){
    (void)n_in; (void)out_size; (void)ws_size;
    const float* cs     = (const float*)d_in[0];
    const int*   label  = (const int*)  d_in[1];
    const float* weight = (const float*)d_in[2];
    const float* logits = (const float*)d_in[3];
    const float* cwb    = (const float*)d_in[4];
    const float* cga    = (const float*)d_in[5];
    const float* wm0    = (const float*)d_in[6];
    float* out = (float*)d_out;
    int N = in_sizes[1];                       // 16384

    // workspace layout (float elements; 16B-aligned)
    float* ws      = (float*)d_ws;
    float* suma    = ws;                       // C    } zeroed by memset
    float* sumb    = suma + C_;                // C    }
    float* S16     = sumb + C_;                // 16C  }
    float* cw2     = S16 + NSGRP * C_;         // C
    float* diagG   = cw2 + C_;                 // C
    float* part1   = diagG + C_;               // NABLK
    float* part2   = part1 + NABLK;            // NABLK
    float* Gpart   = part2 + NABLK;            // 16*C

    hipMemsetAsync(d_ws, 0, (size_t)(2 + NSGRP) * C_ * 4, stream);
    k_pre  <<<1,                     256, 0, stream>>>(logits, cw2, out);
    k_rows <<<NABLK + NGBLK + NDBLK, 256, 0, stream>>>(cs, label, weight, cwb, cw2, cga,
                                                       suma, sumb, S16, part1, part2,
                                                       Gpart, diagG);
    k_last <<<1,                     256, 0, stream>>>(S16, Gpart, diagG, suma, sumb, cw2,
                                                       logits, part1, part2, wm0, out, N);
}

// Round 11
// 143.509 us; speedup vs baseline: 1.7029x; 1.0181x over previous
//
#include <hip/hip_runtime.h>
#include <math.h>

#define C_    1204
#define C4_   301    // C_/4 float4s per row
#define NABLK 512    // A-blocks: 32 rows each (4 waves x 8 rows)
#define NGBLK 80     // G-blocks: cw2^T * cga partials (16 i-chunks x 5 j-tiles)
#define NDBLK 5      // diag blocks: cga[j][j]
#define GYLEN 76     // ceil(1204/16)
#define NSGRP 16     // S atomic contention groups

__device__ __forceinline__ float waveReduceSum(float v){
    #pragma unroll
    for (int o = 32; o > 0; o >>= 1) v += __shfl_xor(v, o, 64);
    return v;
}
__device__ __forceinline__ float4 exp4v(float4 v){
    return float4{__expf(v.x), __expf(v.y), __expf(v.z), __expf(v.w)};
}
__device__ __forceinline__ float hsum4(float4 v){ return v.x + v.y + v.z + v.w; }

// block-wide sumexp of logits (no-max: |logits| <= ~0.05; verified exact in R9)
__device__ __forceinline__ float blockSumExpLogits(const float* __restrict__ logits,
                                                   float* red, int t){
    float s = 0.f;
    #pragma unroll
    for (int k = 0; k < 5; ++k){ int j = t + k * 256; if (j < C_) s += __expf(logits[j]); }
    red[t] = s; __syncthreads();
    for (int o = 128; o > 0; o >>= 1){ if (t < o) red[t] += red[t+o]; __syncthreads(); }
    float r = red[0]; __syncthreads();
    return r;
}

// ---- single pass over cs: sumexp + focal terms + S column-sum, all fused.
//      blocks 0..511: 32 rows each (K computed once per block by wave 0).
//      blocks 512..591: G partials (local elog). blocks 592..596: diagG. ----
__global__ void k_rows(const float* __restrict__ cs, const int* __restrict__ label,
                       const float* __restrict__ w, const float* __restrict__ cwb,
                       const float* __restrict__ logits, const float* __restrict__ cga,
                       float* suma, float* sumb, float* S16,
                       float* __restrict__ part1, float* __restrict__ part2,
                       float* __restrict__ Gpart, float* __restrict__ diagG){
    int b = blockIdx.x;
    int tid = threadIdx.x;

    if (b >= NABLK){
        int gb = b - NABLK;
        if (gb < NGBLK){
            // G-block: Gpart[ic][j] = K * sum_{i in chunk} exp(logits[i])*cga[i][j]
            __shared__ float red[256];
            __shared__ float elog[GYLEN];
            int jt = gb % 5, ic = gb / 5;
            float slog = blockSumExpLogits(logits, red, tid);
            float K = (float)C_ / slog;
            int i0 = ic * GYLEN, i1 = min(i0 + GYLEN, C_);
            if (tid < i1 - i0) elog[tid] = __expf(logits[i0 + tid]);
            __syncthreads();
            int j = jt * 256 + tid;
            if (j < C_){
                float p = 0.f;
                #pragma unroll 4
                for (int i = i0; i < i1; ++i) p += elog[i - i0] * cga[(size_t)i * C_ + j];
                Gpart[ic * C_ + j] = K * p;
            }
        } else {
            int j = (gb - NGBLK) * 256 + tid;
            if (j < C_) diagG[j] = cga[(size_t)j * C_ + j];
        }
        return;
    }

    __shared__ float Sloc[C_];
    __shared__ float lr1[4], lr2[4];
    __shared__ float Kshare;
    int lane = tid & 63, wid = tid >> 6;
    bool has4 = lane < (C4_ - 256);   // 45 tail float4s

    for (int j = tid; j < C_; j += 256) Sloc[j] = 0.f;

    // K computed ONCE per block by wave 0 (logits L2-hot; 5 float4 loads/lane)
    if (wid == 0){
        const float4* lg4 = reinterpret_cast<const float4*>(logits);
        float s = hsum4(exp4v(lg4[lane])) + hsum4(exp4v(lg4[lane + 64]))
                + hsum4(exp4v(lg4[lane + 128])) + hsum4(exp4v(lg4[lane + 192]));
        if (has4) s += hsum4(exp4v(lg4[lane + 256]));
        s = waveReduceSum(s);
        if (lane == 0) Kshare = (float)C_ / s;
    }
    __syncthreads();
    float Klog = Kshare;

    float4 acc0 = {0,0,0,0}, acc1 = {0,0,0,0}, acc2 = {0,0,0,0},
           acc3 = {0,0,0,0}, acc4 = {0,0,0,0};
    float accL = 0.f, accT = 0.f;
    int rowbase = b * 32 + wid * 8;

    #pragma unroll 1
    for (int pr = 0; pr < 4; ++pr){
        int nA = rowbase + pr * 2, nB = nA + 1;
        const float4* rowA = reinterpret_cast<const float4*>(cs + (size_t)nA * C_);
        const float4* rowB = reinterpret_cast<const float4*>(cs + (size_t)nB * C_);

        float4 ea0 = rowA[lane], ea1 = rowA[lane + 64], ea2 = rowA[lane + 128], ea3 = rowA[lane + 192];
        float4 eb0 = rowB[lane], eb1 = rowB[lane + 64], eb2 = rowB[lane + 128], eb3 = rowB[lane + 192];
        float4 ea4 = {0,0,0,0}, eb4 = {0,0,0,0};
        if (has4){ ea4 = rowA[lane + 256]; eb4 = rowB[lane + 256]; }

        ea0 = exp4v(ea0); ea1 = exp4v(ea1); ea2 = exp4v(ea2); ea3 = exp4v(ea3);
        eb0 = exp4v(eb0); eb1 = exp4v(eb1); eb2 = exp4v(eb2); eb3 = exp4v(eb3);
        if (has4){ ea4 = exp4v(ea4); eb4 = exp4v(eb4); }

        float sA = hsum4(ea0) + hsum4(ea1) + hsum4(ea2) + hsum4(ea3) + hsum4(ea4);
        float sB = hsum4(eb0) + hsum4(eb1) + hsum4(eb2) + hsum4(eb3) + hsum4(eb4);
        sA = waveReduceSum(sA);
        sB = waveReduceSum(sB);

        float coefv = 0.f;
        if (lane < 2){
            int   n = (lane == 0) ? nA : nB;
            float s = (lane == 0) ? sA : sB;
            int l = label[n];
            float x = cs[(size_t)n * C_ + l];       // L1-hot, row just streamed
            float logp = x - __logf(s);             // no-max softmax: same math
            float p = __expf(logp);
            float lossc = (1.f - p) * (-logp);      // GAMMA = 1
            float tw = fminf(fmaxf(cwb[l], 1.f/3.f), 5.f);
            float wn = w[n];
            float pp = p + 1e-5f;                   // softmax + 1e-5 at true class
            float fg = wn * ((1.f - pp) / pp - __logf(pp));
            float an = fg * pp;
            atomicAdd(&suma[l], an);
            atomicAdd(&sumb[l], an * pp);
            float c2 = Klog * __expf(logits[l]);    // cw2[l], local (K per block)
            coefv = c2 * an / s;                    // S-weight for this row
            accL += lossc * tw * wn;
            accT += tw;
        }
        float cA = __shfl(coefv, 0, 64);
        float cB = __shfl(coefv, 1, 64);

        acc0.x += cA*ea0.x + cB*eb0.x; acc0.y += cA*ea0.y + cB*eb0.y;
        acc0.z += cA*ea0.z + cB*eb0.z; acc0.w += cA*ea0.w + cB*eb0.w;
        acc1.x += cA*ea1.x + cB*eb1.x; acc1.y += cA*ea1.y + cB*eb1.y;
        acc1.z += cA*ea1.z + cB*eb1.z; acc1.w += cA*ea1.w + cB*eb1.w;
        acc2.x += cA*ea2.x + cB*eb2.x; acc2.y += cA*ea2.y + cB*eb2.y;
        acc2.z += cA*ea2.z + cB*eb2.z; acc2.w += cA*ea2.w + cB*eb2.w;
        acc3.x += cA*ea3.x + cB*eb3.x; acc3.y += cA*ea3.y + cB*eb3.y;
        acc3.z += cA*ea3.z + cB*eb3.z; acc3.w += cA*ea3.w + cB*eb3.w;
        if (has4){
            acc4.x += cA*ea4.x + cB*eb4.x; acc4.y += cA*ea4.y + cB*eb4.y;
            acc4.z += cA*ea4.z + cB*eb4.z; acc4.w += cA*ea4.w + cB*eb4.w;
        }
    }

    // pair-reduce loss terms (lanes 0,1 hold per-row values)
    accL += __shfl_xor(accL, 1, 64);
    accT += __shfl_xor(accT, 1, 64);
    if (lane == 0){ lr1[wid] = accL; lr2[wid] = accT; }

    // wave-sequential accumulation into Sloc (no LDS atomics)
    float4* Sloc4 = reinterpret_cast<float4*>(Sloc);
    __syncthreads();
    #pragma unroll
    for (int wv = 0; wv < 4; ++wv){
        if (wid == wv){
            float4 t0 = Sloc4[lane      ]; t0.x+=acc0.x; t0.y+=acc0.y; t0.z+=acc0.z; t0.w+=acc0.w; Sloc4[lane      ] = t0;
            float4 t1 = Sloc4[lane +  64]; t1.x+=acc1.x; t1.y+=acc1.y; t1.z+=acc1.z; t1.w+=acc1.w; Sloc4[lane +  64] = t1;
            float4 t2 = Sloc4[lane + 128]; t2.x+=acc2.x; t2.y+=acc2.y; t2.z+=acc2.z; t2.w+=acc2.w; Sloc4[lane + 128] = t2;
            float4 t3 = Sloc4[lane + 192]; t3.x+=acc3.x; t3.y+=acc3.y; t3.z+=acc3.z; t3.w+=acc3.w; Sloc4[lane + 192] = t3;
            if (has4){
                float4 t4 = Sloc4[lane + 256]; t4.x+=acc4.x; t4.y+=acc4.y; t4.z+=acc4.z; t4.w+=acc4.w; Sloc4[lane + 256] = t4;
            }
        }
        __syncthreads();
    }

    // block partial -> grouped global atomics (32 blocks/address)
    float* Sg = S16 + (size_t)(b & (NSGRP - 1)) * C_;
    for (int j = tid; j < C_; j += 256) atomicAdd(&Sg[j], Sloc[j]);

    if (tid == 0){
        part1[b] = lr1[0] + lr1[1] + lr1[2] + lr1[3];
        part2[b] = lr2[0] + lr2[1] + lr2[2] + lr2[3];
    }
}

// ---- last: cw2 (local K), loss partials, E, closed forms, tcw, outputs ----
__global__ void k_last(const float* __restrict__ S16, const float* __restrict__ Gpart,
                       const float* __restrict__ diagG, const float* __restrict__ suma,
                       const float* __restrict__ sumb, const float* __restrict__ logits,
                       const float* __restrict__ part1, const float* __restrict__ part2,
                       const float* __restrict__ wm0, float* out, int Nn){
    __shared__ float tcw[C_];
    __shared__ float red[256];
    __shared__ float red2[256];
    int t = threadIdx.x;

    float slog = blockSumExpLogits(logits, red, t);
    float K = (float)C_ / slog;

    float p1 = 0.f, p2 = 0.f;
    for (int k = t; k < NABLK; k += 256){ p1 += part1[k]; p2 += part2[k]; }
    red[t] = p1; red2[t] = p2; __syncthreads();
    for (int o = 128; o > 0; o >>= 1){
        if (t < o){ red[t] += red[t+o]; red2[t] += red2[t+o]; }
        __syncthreads();
    }
    float sumLoss = red[0], sumT = red2[0];
    __syncthreads();

    // cw2 out-writes + E = 1e-5 * dot(cw2, suma)
    float pe = 0.f;
    #pragma unroll
    for (int k = 0; k < 5; ++k){
        int j = t + k * 256;
        if (j < C_){
            float c2 = K * __expf(logits[j]);
            out[2 + j] = c2;
            pe += c2 * suma[j];
        }
    }
    red[t] = pe; __syncthreads();
    for (int o = 128; o > 0; o >>= 1){ if (t < o) red[t] += red[t+o]; __syncthreads(); }
    float E = red[0] * 1e-5f;
    __syncthreads();

    float scale = 100.f / (float)Nn;
    float psum = 0.f;
    #pragma unroll
    for (int k = 0; k < 5; ++k){
        int j = t + k * 256;
        if (j < C_ - 1){
            float c2 = K * __expf(logits[j]);
            float G = 0.f;
            #pragma unroll
            for (int y = 0; y < 16; ++y) G += Gpart[y * C_ + j];
            float Sj = 0.f;
            #pragma unroll
            for (int g = 0; g < NSGRP; ++g) Sj += S16[g * C_ + j];
            float tcol  = 0.999f * G + 0.001f * scale * (Sj + E - c2 * suma[j]);
            float diagA = 0.999f * diagG[j] - 0.001f * scale * (suma[j] - sumb[j]);
            float v = tcol / (-diagA + 1e-6f) + c2;
            tcw[j] = v; psum += v;           // sum of UNclipped first C-1 values
        }
    }
    red[t] = psum; __syncthreads();
    for (int o = 128; o > 0; o >>= 1){ if (t < o) red[t] += red[t+o]; __syncthreads(); }
    if (t == 0) tcw[C_ - 1] = (float)C_ - red[0];
    __syncthreads();
    float sq = 0.f;
    #pragma unroll
    for (int k = 0; k < 5; ++k){
        int j = t + k * 256;
        if (j < C_){
            float hi = (j == C_ - 1) ? 1.f : 5.f;   // clip(.,1/3,5); last clip(.,1/3,1)
            float v = fminf(fmaxf(tcw[j], 1.f/3.f), hi);
            float d = logf(v) - logits[j];
            sq += d * d;
        }
    }
    red[t] = sq; __syncthreads();
    for (int o = 128; o > 0; o >>= 1){ if (t < o) red[t] += red[t+o]; __syncthreads(); }
    if (t == 0){
        float wm = 0.999f * wm0[0] + 0.001f * (sumT / (float)Nn);
        out[0] = sumLoss / ((float)Nn * wm);   // loss (SELF_LOSS_WEIGHT = 1)
        out[1] = red[0] / (float)C_;           // loss_grad
    }
}

extern "C" void kernel_launch(void* const* d_in, const int* in_sizes, int n_in,
                              void* d_out, int out_size, void* d_ws, size_t ws_size,
                              hipStream_t stream){
    (void)n_in; (void)out_size; (void)ws_size;
    const float* cs     = (const float*)d_in[0];
    const int*   label  = (const int*)  d_in[1];
    const float* weight = (const float*)d_in[2];
    const float* logits = (const float*)d_in[3];
    const float* cwb    = (const float*)d_in[4];
    const float* cga    = (const float*)d_in[5];
    const float* wm0    = (const float*)d_in[6];
    float* out = (float*)d_out;
    int N = in_sizes[1];                       // 16384

    // workspace layout (float elements; 16B-aligned)
    float* ws      = (float*)d_ws;
    float* suma    = ws;                       // C    } zeroed by memset
    float* sumb    = suma + C_;                // C    }
    float* S16     = sumb + C_;                // 16C  }
    float* diagG   = S16 + NSGRP * C_;         // C
    float* part1   = diagG + C_;               // NABLK
    float* part2   = part1 + NABLK;            // NABLK
    float* Gpart   = part2 + NABLK;            // 16*C

    hipMemsetAsync(d_ws, 0, (size_t)(2 + NSGRP) * C_ * 4, stream);
    k_rows <<<NABLK + NGBLK + NDBLK, 256, 0, stream>>>(cs, label, weight, cwb, logits, cga,
                                                       suma, sumb, S16, part1, part2,
                                                       Gpart, diagG);
    k_last <<<1,                     256, 0, stream>>>(S16, Gpart, diagG, suma, sumb,
                                                       logits, part1, part2, wm0, out, N);
}